// Round 17
// baseline (115.259 us; speedup 1.0000x reference)
//
#include <hip/hip_runtime.h>
#include <hip/hip_bf16.h>

// TripletBatchHardLoss: N=8192, D=256, fp32 embeddings (L2-normalized), int32 labels.
// Normalized -> pdist monotone DECREASING in dot:
//   hard_negative = max dot over negs, hard_positive = min dot over poss (diag dot~1 safe).
// R17: ZERO-SYNC K-loop via full-K LDS residency. 2080 upper-triangle 128x128 blocks;
// stage ENTIRE A-strip (128x256=64KB) + B-strip (64KB) = 128 KB static LDS (gfx950
// LocalMemorySize=163840) via 32 global_load_lds per wave; ONE vmcnt(0)+barrier; then
// 8 K-steps of pure ds_read+MFMA with NO barriers/waits -- compiler free to hoist kt+1
// reads into kt's MFMA shadow. 3 barriers/block total vs R15's 16. 1 block/CU accepted.
// Epilogue: R15/R16 LDS-combine (atomics ~10 wave-instrs; WRITE_SIZE 3 MB verified R16)
// with WAR __syncthreads before scratch reuse.
// Discipline: no launch_bounds min-waves (R7/R10: (256,4)=64 VGPR spills, (256,5)=48);
// no __threadfence in wide kernels (R11: per-block fence = per-XCD L2 writeback +130 us).

#define NS 8192
#define DD 256
#define EPS_PD 1e-12f
#define BIGF 1e30f

typedef unsigned short u16;
typedef unsigned int u32;
typedef short short8 __attribute__((ext_vector_type(8)));
typedef float f32x4 __attribute__((ext_vector_type(4)));

typedef const __attribute__((address_space(1))) u32 glb_u32;
typedef __attribute__((address_space(3))) u32 lds_u32;

__device__ __forceinline__ void async16(const void* g, void* l) {
    __builtin_amdgcn_global_load_lds((glb_u32*)g, (lds_u32*)l, 16, 0, 0);
}

// order-preserving float <-> uint key (unsigned compare == float compare)
__device__ __forceinline__ u32 fkey(float f) {
    u32 b = __float_as_uint(f);
    return (b & 0x80000000u) ? ~b : (b | 0x80000000u);
}
__device__ __forceinline__ float unkey(u32 k) {
    u32 b = (k & 0x80000000u) ? (k ^ 0x80000000u) : ~k;
    return __uint_as_float(b);
}

__device__ __forceinline__ u16 f2bf_rne(float f) {
    u32 b = __float_as_uint(f);
    b += 0x7FFFu + ((b >> 16) & 1u);
    return (u16)(b >> 16);
}

// DPP lane-move within 16-lane rows (reduction groups are exactly DPP rows)
template <int CTRL>
__device__ __forceinline__ float dpp_mov(float x) {
    return __int_as_float(
        __builtin_amdgcn_update_dpp(0, __float_as_int(x), CTRL, 0xF, 0xF, true));
}

// ---------------- kernel 1: fp32 -> bf16, row sum-of-squares, init keys ----------------
__global__ __launch_bounds__(256) void prep_kernel(
    const float* __restrict__ e, u16* __restrict__ ebf, float* __restrict__ sq,
    u32* __restrict__ mxk, u32* __restrict__ mnk, float* __restrict__ out) {
    const int tid = blockIdx.x * 256 + threadIdx.x;   // 2048 blocks
    const int row = tid >> 6, t = tid & 63;           // one wave per row
    float4 v = ((const float4*)(e + (size_t)row * DD))[t];
    ushort4 u;
    u.x = f2bf_rne(v.x); u.y = f2bf_rne(v.y); u.z = f2bf_rne(v.z); u.w = f2bf_rne(v.w);
    ((ushort4*)(ebf + (size_t)row * DD))[t] = u;
    float s = v.x * v.x + v.y * v.y + v.z * v.z + v.w * v.w;
    for (int o = 32; o; o >>= 1) s += __shfl_down(s, o);
    if (t == 0) {
        sq[row] = s;
        mxk[row] = 0u;            // sentinel for unsigned max
        mnk[row] = 0xFFFFFFFFu;   // sentinel for unsigned min
        if (row == 0) out[0] = 0.0f;
    }
}

// ------- kernel 2: full-K-resident zero-sync dot-GEMM + reduction + LDS combine ---------
__global__ __launch_bounds__(256) void tile_kernel(
    const u16* __restrict__ ebf, const int* __restrict__ labels,
    u32* __restrict__ mxk, u32* __restrict__ mnk) {
    // full 128x256 strips; 16B chunk (row,c) at slot row*32 + (c ^ (row&7))
    __shared__ __attribute__((aligned(16))) u16 lds_a[128 * 256];   // 64 KB
    __shared__ __attribute__((aligned(16))) u16 lds_b[128 * 256];   // 64 KB

    // decode linear triangle index -> (i <= j)
    const int t = blockIdx.x;
    int j = (int)((sqrtf(8.0f * (float)t + 1.0f) - 1.0f) * 0.5f);
    while ((j + 1) * (j + 2) / 2 <= t) ++j;
    while (j * (j + 1) / 2 > t) --j;
    const int i = t - j * (j + 1) / 2;
    const int bi = i * 128, bj = j * 128;

    const int tid = threadIdx.x;
    const int lane = tid & 63, wid = tid >> 6;
    const int wm = wid >> 1, wn = wid & 1;
    const int l15 = lane & 15, q = lane >> 4;

    // ---- stage both strips: 4096 chunks each; wave wid, instr it covers
    // slots s = (it*4+wid)*64 + lane (DMA lands base + lane*16B, contiguous slots)
#pragma unroll
    for (int it = 0; it < 16; ++it) {
        const int sb = (it * 4 + wid) * 64;
        const int s = sb + lane;
        const int row = s >> 5, sc = s & 31, c = sc ^ (row & 7);
        async16(ebf + (size_t)(bi + row) * DD + c * 8, lds_a + sb * 8);
        async16(ebf + (size_t)(bj + row) * DD + c * 8, lds_b + sb * 8);
    }
    asm volatile("s_waitcnt vmcnt(0)" ::: "memory");
    __syncthreads();   // barrier 1 of 3: strips resident for all waves

    // frag reads: row = base + l15; chunk (kt*4+q) -> slot row*32 + ((kt*4+q)^(row&7))
    const int rowa = wm * 64 + l15, rowb = wn * 64 + l15;
    f32x4 acc[4][4] = {};
#pragma unroll
    for (int kt = 0; kt < 8; ++kt) {
        short8 af[4], bfr[4];
#pragma unroll
        for (int mi = 0; mi < 4; ++mi) {
            const int r = rowa + mi * 16;
            af[mi] = *(const short8*)(lds_a + (r * 32 + ((kt * 4 + q) ^ (r & 7))) * 8);
        }
#pragma unroll
        for (int ni = 0; ni < 4; ++ni) {
            const int r = rowb + ni * 16;
            bfr[ni] = *(const short8*)(lds_b + (r * 32 + ((kt * 4 + q) ^ (r & 7))) * 8);
        }
#pragma unroll
        for (int mi = 0; mi < 4; ++mi)
#pragma unroll
            for (int ni = 0; ni < 4; ++ni)
                acc[mi][ni] = __builtin_amdgcn_mfma_f32_16x16x32_bf16(
                    af[mi], bfr[ni], acc[mi][ni], 0, 0, 0);
    }

    // ---- epilogue: C/D layout col = lane&15, row = q*4 + reg (m89-verified) ----
    int li[4][4];
#pragma unroll
    for (int mi = 0; mi < 4; ++mi) {
        const int4 v = *(const int4*)(labels + bi + wm * 64 + mi * 16 + q * 4);
        li[mi][0] = v.x; li[mi][1] = v.y; li[mi][2] = v.z; li[mi][3] = v.w;
    }
    int lj[4];
#pragma unroll
    for (int ni = 0; ni < 4; ++ni) lj[ni] = labels[bj + wn * 64 + ni * 16 + l15];

    float mxn[4][4], mnp[4][4];                        // row-side per (mi, r)
    float mxc[4] = {-BIGF, -BIGF, -BIGF, -BIGF};       // col-side per ni
    float mnc[4] = {BIGF, BIGF, BIGF, BIGF};
#pragma unroll
    for (int mi = 0; mi < 4; ++mi)
#pragma unroll
        for (int r2 = 0; r2 < 4; ++r2) { mxn[mi][r2] = -BIGF; mnp[mi][r2] = BIGF; }

#pragma unroll
    for (int mi = 0; mi < 4; ++mi)
#pragma unroll
        for (int ni = 0; ni < 4; ++ni) {
            const int l = lj[ni];
#pragma unroll
            for (int r2 = 0; r2 < 4; ++r2) {
                const float d = acc[mi][ni][r2];
                const bool same = (li[mi][r2] == l);
                const float sneg = same ? -BIGF : d;
                const float spos = same ? d : BIGF;
                mxn[mi][r2] = fmaxf(mxn[mi][r2], sneg);
                mnp[mi][r2] = fminf(mnp[mi][r2], spos);
                mxc[ni] = fmaxf(mxc[ni], sneg);
                mnc[ni] = fminf(mnc[ni], spos);
            }
        }

    // col-side: reduce over q (lanes l15, +16, +32, +48) via shfl_xor 16/32
#pragma unroll
    for (int ni = 0; ni < 4; ++ni) {
        mxc[ni] = fmaxf(mxc[ni], __shfl_xor(mxc[ni], 16));
        mnc[ni] = fminf(mnc[ni], __shfl_xor(mnc[ni], 16));
        mxc[ni] = fmaxf(mxc[ni], __shfl_xor(mxc[ni], 32));
        mnc[ni] = fminf(mnc[ni], __shfl_xor(mnc[ni], 32));
    }
    // row-side: 16-lane DPP reduction (xor1, xor2, ror4, ror8)
#pragma unroll
    for (int mi = 0; mi < 4; ++mi)
#pragma unroll
        for (int r2 = 0; r2 < 4; ++r2) {
            float x = mxn[mi][r2], n = mnp[mi][r2];
            x = fmaxf(x, dpp_mov<0xB1>(x));  n = fminf(n, dpp_mov<0xB1>(n));
            x = fmaxf(x, dpp_mov<0x4E>(x));  n = fminf(n, dpp_mov<0x4E>(n));
            x = fmaxf(x, dpp_mov<0x124>(x)); n = fminf(n, dpp_mov<0x128>(n));
            x = fmaxf(x, dpp_mov<0x128>(x)); n = fminf(n, dpp_mov<0x124>(n));
            mxn[mi][r2] = x; mnp[mi][r2] = n;
        }

    // ---- block-level LDS combine -> 8 atomic wave-instrs (WRITE_SIZE ~3 MB, R16) ----
    __syncthreads();   // barrier 2 of 3: WAR — all waves done reading lds_a before reuse
    float* red = (float*)lds_a;   // 4 KB scratch
    if (l15 == 0) {
#pragma unroll
        for (int mi = 0; mi < 4; ++mi)
#pragma unroll
            for (int r2 = 0; r2 < 4; ++r2) {
                const int rl = wm * 64 + mi * 16 + q * 4 + r2;
                red[rl * 2 + wn] = mxn[mi][r2];
                red[256 + rl * 2 + wn] = mnp[mi][r2];
            }
    }
    if (q == 0) {
#pragma unroll
        for (int ni = 0; ni < 4; ++ni) {
            const int cl = wn * 64 + ni * 16 + l15;
            red[512 + cl * 2 + wm] = mxc[ni];
            red[768 + cl * 2 + wm] = mnc[ni];
        }
    }
    __syncthreads();   // barrier 3 of 3
    if (tid < 128) {
        const float mx = fmaxf(red[tid * 2], red[tid * 2 + 1]);
        const float mn = fminf(red[256 + tid * 2], red[256 + tid * 2 + 1]);
        atomicMax(&mxk[bi + tid], fkey(mx));
        atomicMin(&mnk[bi + tid], fkey(mn));
    } else {
        const int c = tid - 128;
        const float mx = fmaxf(red[512 + c * 2], red[512 + c * 2 + 1]);
        const float mn = fminf(red[768 + c * 2], red[768 + c * 2 + 1]);
        atomicMax(&mxk[bj + c], fkey(mx));
        atomicMin(&mnk[bj + c], fkey(mn));
    }
}

// ---------------- kernel 3: per-row loss + mean ----------------
__global__ __launch_bounds__(256) void finalize_kernel(
    const u32* __restrict__ mxk, const u32* __restrict__ mnk,
    const float* __restrict__ sq, float* __restrict__ out) {
    const int i = blockIdx.x * 256 + threadIdx.x;
    const float s = sq[i] + 1.0f;   // sq_i + sq_j, sq_j = 1 +- 1e-7
    const float hn = sqrtf(fmaxf(fmaf(-2.0f, unkey(mxk[i]), s), EPS_PD));
    const float hp = sqrtf(fmaxf(fmaf(-2.0f, unkey(mnk[i]), s), EPS_PD));
    float loss = fmaxf(hp - hn + 1.0f, 0.0f);
    for (int o = 32; o; o >>= 1) loss += __shfl_down(loss, o);
    __shared__ float wsum[4];
    const int lane = threadIdx.x & 63, w = threadIdx.x >> 6;
    if (lane == 0) wsum[w] = loss;
    __syncthreads();
    if (threadIdx.x == 0)
        atomicAdd(out, (wsum[0] + wsum[1] + wsum[2] + wsum[3]) * (1.0f / NS));
}

extern "C" void kernel_launch(void* const* d_in, const int* in_sizes, int n_in,
                              void* d_out, int out_size, void* d_ws, size_t ws_size,
                              hipStream_t stream) {
    const int* labels = (const int*)d_in[0];
    const float* emb = (const float*)d_in[1];
    float* out = (float*)d_out;

    char* ws = (char*)d_ws;
    u16* ebf = (u16*)ws;                                     // 4 MB
    float* sq = (float*)(ws + (size_t)NS * DD * 2);          // 32 KB
    u32* mxk = (u32*)(ws + (size_t)NS * DD * 2 + NS * 4);
    u32* mnk = mxk + NS;

    prep_kernel<<<NS * DD / 4 / 256, 256, 0, stream>>>(emb, ebf, sq, mxk, mnk, out);
    tile_kernel<<<2080, 256, 0, stream>>>(ebf, labels, mxk, mnk);
    finalize_kernel<<<NS / 256, 256, 0, stream>>>(mxk, mnk, sq, out);
}